// Round 4
// baseline (98.762 us; speedup 1.0000x reference)
//
#include <hip/hip_runtime.h>
#include <math.h>

// ConvCapsule R4: 4-pixel tile per 512-thread block (2048 blocks).
// bf16 MFMA conv (A = im2col patch, B = weights; wave owns 32-oa panel so the
// block reads W exactly once = 114KB -> 235MB total L2 traffic, was 940MB).
// Routing per thread on 2 register-resident vote rows, DPP reductions.

using short8 = __attribute__((ext_vector_type(8))) short;
using f32x4  = __attribute__((ext_vector_type(4))) float;

__device__ __forceinline__ unsigned short f2bf(float f) {
    unsigned u = __float_as_uint(f);
    return (unsigned short)((u + 0x7fffu + ((u >> 16) & 1u)) >> 16);  // RNE
}

template<int CTRL>
__device__ __forceinline__ float dpp_movf(float x) {
    return __int_as_float(__builtin_amdgcn_update_dpp(
        0, __float_as_int(x), CTRL, 0xF, 0xF, true));
}
__device__ __forceinline__ float sum8(float x) {
    x += dpp_movf<0xB1>(x);    // quad_perm [1,0,3,2]
    x += dpp_movf<0x4E>(x);    // quad_perm [2,3,0,1]
    x += dpp_movf<0x141>(x);   // row_half_mirror
    return x;
}
__device__ __forceinline__ float max8(float x) {
    x = fmaxf(x, dpp_movf<0xB1>(x));
    x = fmaxf(x, dpp_movf<0x4E>(x));
    x = fmaxf(x, dpp_movf<0x141>(x));
    return x;
}

// ---------- prep 1: W -> bf16, [s(7)][g(4)][oa(256)][j(8)], k = s*32+g*8+j ----------
__global__ __launch_bounds__(256)
void prep_w(const float* __restrict__ cw, unsigned short* __restrict__ wp) {
    const int idx = blockIdx.x * 256 + threadIdx.x;   // 57344 total
    const int j  = idx & 7;
    const int oa = (idx >> 3) & 255;
    const int g  = (idx >> 11) & 3;
    const int s  = idx >> 13;
    const int k  = s * 32 + g * 8 + j;
    wp[idx] = (k < 200) ? f2bf(cw[k * 256 + oa]) : (unsigned short)0;
}

// ---------- prep 2: x -> bf16 transposed [b][y][x][i*8+ci] ----------
__global__ __launch_bounds__(256)
void prep_x(const float* __restrict__ x, unsigned short* __restrict__ xt) {
    __shared__ unsigned short tile[32 * 256];         // [xx][plane]
    const int t = threadIdx.x;                        // plane = i*8+ci
    const int b = blockIdx.x >> 5, y = blockIdx.x & 31;
    const float* src = x + (((size_t)((b << 8) + t)) << 10) + (y << 5);
    #pragma unroll
    for (int c = 0; c < 8; ++c) {
        float4 v = *(const float4*)(src + c * 4);
        tile[(c * 4 + 0) * 256 + t] = f2bf(v.x);
        tile[(c * 4 + 1) * 256 + t] = f2bf(v.y);
        tile[(c * 4 + 2) * 256 + t] = f2bf(v.z);
        tile[(c * 4 + 3) * 256 + t] = f2bf(v.w);
    }
    __syncthreads();
    unsigned short* dst = xt + ((size_t)blockIdx.x << 13);
    #pragma unroll
    for (int c = 0; c < 4; ++c) {
        const int chunk = t + c * 256;
        *(short8*)(dst + chunk * 8) = *(const short8*)(&tile[chunk * 8]);
    }
}

// ---------- main fused kernel: 4 pixels / 512 threads ----------
__global__ __launch_bounds__(512, 4)
void capsule_mfma4(const unsigned short* __restrict__ xt,
                   const unsigned short* __restrict__ wp,
                   const float* __restrict__ conv_b,
                   const float* __restrict__ biases,
                   float* __restrict__ out)
{
    // Overlaid LDS phases (36864 B):
    //   A: patch [32 i][40 pos][8 ci] bf16, row 656 B  (20992 B)
    //   B: vtr   per-wave float[32 oal][36]            (8 x 4608 B)
    //   C: route_q [32 o][36] f32 at q*4608 ; logits_q at 18432 + q*4608
    __shared__ __align__(16) char lds[36864];

    const int t   = threadIdx.x;
    const int blk = blockIdx.x;           // 2048
    const int b   = blk >> 8;
    const int rem = blk & 255;
    const int h   = rem >> 3;
    const int w0  = (rem & 7) << 2;       // pixels w0..w0+3

    // ---- stage patch: 40 taps (5 ky x 8 xl) x 32 i, 16B per unit ----
    for (int u = t; u < 1280; u += 512) {
        const int i = u & 31, pos = u >> 5;
        const int ky = pos >> 3, xl = pos & 7;
        const int y = h + ky - 2, xx = w0 + xl - 2;
        short8 v = {0, 0, 0, 0, 0, 0, 0, 0};
        if ((unsigned)y < 32u && (unsigned)xx < 32u)
            v = *(const short8*)(xt + (((size_t)(((b << 5) + y) << 5) + xx) << 8) + i * 8);
        *(short8*)(lds + i * 656 + pos * 16) = v;
    }

    const int l  = t & 63, wv = t >> 6;   // 8 waves
    const int lm = l & 15, lg = l >> 4;

    // conv: M = i (A = patch), N = oa (B = W, wave owns 32 oa), K = 224
    f32x4 acc[2][2][4];                   // [mt(i-half)][nt(oa-16)][q]
    #pragma unroll
    for (int mt = 0; mt < 2; ++mt)
        #pragma unroll
        for (int nt = 0; nt < 2; ++nt)
            #pragma unroll
            for (int q = 0; q < 4; ++q)
                acc[mt][nt][q] = (f32x4){0.f, 0.f, 0.f, 0.f};

    __syncthreads();   // patch ready

    const unsigned short* wb = wp + lg * 2048 + (((wv << 5) + lm) << 3);
    const char* arow = lds + lm * 656;

    for (int s = 0; s < 7; ++s) {
        const short8 bw0 = *(const short8*)(wb + s * 8192);
        const short8 bw1 = *(const short8*)(wb + s * 8192 + 128);
        const int kt = s * 4 + lg;        // tap index; k = s*32+lg*8+j
        int pos0 = 0;
        if (kt <= 24) { const int ky = kt / 5; pos0 = ky * 8 + (kt - ky * 5); }
        // kt>24: W slice is zero -> A may be junk (finite), product is 0
        const char* abase = arow + pos0 * 16;
        #pragma unroll
        for (int qq = 0; qq < 2; ++qq) {
            const short8 a00 = *(const short8*)(abase + (qq * 2 + 0) * 16);
            const short8 a01 = *(const short8*)(abase + (qq * 2 + 1) * 16);
            const short8 a10 = *(const short8*)(abase + 10496 + (qq * 2 + 0) * 16);
            const short8 a11 = *(const short8*)(abase + 10496 + (qq * 2 + 1) * 16);
            acc[0][0][qq*2+0] = __builtin_amdgcn_mfma_f32_16x16x32_bf16(a00, bw0, acc[0][0][qq*2+0], 0, 0, 0);
            acc[0][1][qq*2+0] = __builtin_amdgcn_mfma_f32_16x16x32_bf16(a00, bw1, acc[0][1][qq*2+0], 0, 0, 0);
            acc[1][0][qq*2+0] = __builtin_amdgcn_mfma_f32_16x16x32_bf16(a10, bw0, acc[1][0][qq*2+0], 0, 0, 0);
            acc[1][1][qq*2+0] = __builtin_amdgcn_mfma_f32_16x16x32_bf16(a10, bw1, acc[1][1][qq*2+0], 0, 0, 0);
            acc[0][0][qq*2+1] = __builtin_amdgcn_mfma_f32_16x16x32_bf16(a01, bw0, acc[0][0][qq*2+1], 0, 0, 0);
            acc[0][1][qq*2+1] = __builtin_amdgcn_mfma_f32_16x16x32_bf16(a01, bw1, acc[0][1][qq*2+1], 0, 0, 0);
            acc[1][0][qq*2+1] = __builtin_amdgcn_mfma_f32_16x16x32_bf16(a11, bw0, acc[1][0][qq*2+1], 0, 0, 0);
            acc[1][1][qq*2+1] = __builtin_amdgcn_mfma_f32_16x16x32_bf16(a11, bw1, acc[1][1][qq*2+1], 0, 0, 0);
        }
    }

    __syncthreads();   // all patch reads done; lds reusable for vtr

    // ---- transpose: C layout lane holds col oa = nt*16+lm, rows i = mt*16+lg*4+r ----
    float* vtrw = (float*)lds + wv * 1152;           // [32 oal][36]
    const int oa_own = t & 255;
    const int p0 = t >> 8;                            // pixels {p0, p0+2}
    const float* vsrc = (float*)lds + (oa_own >> 5) * 1152 + (oa_own & 31) * 36;
    float v0[32], v1[32];

    #pragma unroll
    for (int q = 0; q < 4; ++q) {
        #pragma unroll
        for (int mt = 0; mt < 2; ++mt)
            #pragma unroll
            for (int nt = 0; nt < 2; ++nt)
                *(f32x4*)(vtrw + ((nt << 4) + lm) * 36 + (mt << 4) + (lg << 2)) = acc[mt][nt][q];
        __syncthreads();
        if ((q & 1) == p0) {
            if (q < 2) {
                #pragma unroll
                for (int c = 0; c < 8; ++c) {
                    const f32x4 vv = *(const f32x4*)(vsrc + c * 4);
                    v0[c*4+0] = vv[0]; v0[c*4+1] = vv[1]; v0[c*4+2] = vv[2]; v0[c*4+3] = vv[3];
                }
            } else {
                #pragma unroll
                for (int c = 0; c < 8; ++c) {
                    const f32x4 vv = *(const f32x4*)(vsrc + c * 4);
                    v1[c*4+0] = vv[0]; v1[c*4+1] = vv[1]; v1[c*4+2] = vv[2]; v1[c*4+3] = vv[3];
                }
            }
        }
        __syncthreads();
    }

    // ---- fold conv bias; rowsums for iter-0 (route == 1/33 uniform) ----
    const float cb = conv_b[oa_own];
    float rs0 = 0.f, rs1 = 0.f;
    #pragma unroll
    for (int i = 0; i < 32; ++i) {
        v0[i] += cb; rs0 += v0[i];
        v1[i] += cb; rs1 += v1[i];
    }

    const int o_t = oa_own >> 3, a_t = t & 7;
    const float bias_v = biases[oa_own];
    const int q0 = p0, q1 = p0 + 2;
    float* route0 = (float*)lds + q0 * 1152;
    float* route1 = (float*)lds + q1 * 1152;
    float* logit0 = (float*)lds + 4608 + q0 * 1152;
    float* logit1 = (float*)lds + 4608 + q1 * 1152;
    float actv0 = 0.f, actv1 = 0.f;

#define PREACT(VV, RT, RS, ACT) do {                                          \
    float pre;                                                                \
    if (it == 0) pre = fmaf(RS, 1.f / 33.f, bias_v);                          \
    else {                                                                    \
        pre = bias_v;                                                         \
        const float* rrow = RT + o_t * 36;                                    \
        _Pragma("unroll")                                                     \
        for (int c = 0; c < 8; ++c) {                                         \
            const f32x4 rv = *(const f32x4*)(rrow + c * 4);                   \
            pre = fmaf(VV[c*4+0], rv[0], pre);                                \
            pre = fmaf(VV[c*4+1], rv[1], pre);                                \
            pre = fmaf(VV[c*4+2], rv[2], pre);                                \
            pre = fmaf(VV[c*4+3], rv[3], pre);                                \
        }                                                                     \
    }                                                                         \
    const float ns = sum8(pre * pre);                                         \
    ACT = pre * sqrtf(ns) / (1.f + ns);                                       \
} while (0)

#define DSUM(VV, ACT, LG) do {                                                \
    float ds_[32];                                                            \
    _Pragma("unroll")                                                         \
    for (int i = 0; i < 32; ++i) ds_[i] = sum8(VV[i] * ACT);                  \
    if (a_t == 0) {                                                           \
        float* lrow = LG + o_t * 36;                                          \
        _Pragma("unroll")                                                     \
        for (int c = 0; c < 8; ++c) {                                         \
            f32x4 cur;                                                        \
            if (it == 0) cur = (f32x4){0.f, 0.f, 0.f, 0.f};                   \
            else cur = *(const f32x4*)(lrow + c * 4);                         \
            cur[0] += ds_[c*4+0]; cur[1] += ds_[c*4+1];                       \
            cur[2] += ds_[c*4+2]; cur[3] += ds_[c*4+3];                       \
            *(f32x4*)(lrow + c * 4) = cur;                                    \
        }                                                                     \
    }                                                                         \
} while (0)

#define SOFTMAX(LG, RT) do {                                                  \
    const int r = o_t, sub = a_t;                                             \
    float e0 = LG[(sub * 4 + 0) * 36 + r];                                    \
    float e1 = LG[(sub * 4 + 1) * 36 + r];                                    \
    float e2 = LG[(sub * 4 + 2) * 36 + r];                                    \
    float e3 = LG[(sub * 4 + 3) * 36 + r];                                    \
    float mx = fmaxf(fmaxf(e0, e1), fmaxf(e2, e3));                           \
    mx = max8(fmaxf(mx, 0.f));                                                \
    e0 = __expf(e0 - mx); e1 = __expf(e1 - mx);                               \
    e2 = __expf(e2 - mx); e3 = __expf(e3 - mx);                               \
    const float ssum = sum8(e0 + e1 + e2 + e3) + __expf(-mx);                 \
    const float inv = 1.f / ssum;                                             \
    RT[(sub * 4 + 0) * 36 + r] = e0 * inv;                                    \
    RT[(sub * 4 + 1) * 36 + r] = e1 * inv;                                    \
    RT[(sub * 4 + 2) * 36 + r] = e2 * inv;                                    \
    RT[(sub * 4 + 3) * 36 + r] = e3 * inv;                                    \
} while (0)

    #pragma unroll
    for (int it = 0; it < 3; ++it) {
        PREACT(v0, route0, rs0, actv0);
        PREACT(v1, route1, rs1, actv1);
        if (it < 2) {
            DSUM(v0, actv0, logit0);
            DSUM(v1, actv1, logit1);
            __syncthreads();
            SOFTMAX(logit0, route0);
            SOFTMAX(logit1, route1);
            __syncthreads();
        }
    }

    // out[b][o][pix][a]
    const int pixb = (h << 5) + w0;
    const size_t obase = ((size_t)((b << 5) + o_t) << 13) + a_t;
    out[obase + ((size_t)(pixb + q0) << 3)] = actv0;
    out[obase + ((size_t)(pixb + q1) << 3)] = actv1;
}

extern "C" void kernel_launch(void* const* d_in, const int* in_sizes, int n_in,
                              void* d_out, int out_size, void* d_ws, size_t ws_size,
                              hipStream_t stream) {
    const float* x      = (const float*)d_in[0];
    const float* conv_w = (const float*)d_in[1];
    const float* conv_b = (const float*)d_in[2];
    const float* biases = (const float*)d_in[3];
    unsigned short* wp = (unsigned short*)d_ws;                     // 114,688 B
    unsigned short* xt = (unsigned short*)((char*)d_ws + 131072);   // 4 MB
    prep_w<<<dim3(224), dim3(256), 0, stream>>>(conv_w, wp);
    prep_x<<<dim3(256), dim3(256), 0, stream>>>(x, xt);
    capsule_mfma4<<<dim3(2048), dim3(512), 0, stream>>>(xt, wp, conv_b, biases, (float*)d_out);
}